// Round 11
// baseline (266.029 us; speedup 1.0000x reference)
//
#include <hip/hip_runtime.h>
#include <hip/hip_fp16.h>
#include <stdint.h>

#define T_FRAMES 3
#define NTOK 4096
#define CH 256

typedef __attribute__((ext_vector_type(8))) short bf16x8;
typedef __attribute__((ext_vector_type(4))) float f32x4;
typedef __attribute__((address_space(1))) void gvoid;
typedef __attribute__((address_space(3))) void svoid;

__device__ __forceinline__ unsigned short f2bf_rne(float f) {
  union { float f; uint32_t u; } c; c.f = f;
  uint32_t u = c.u;
  return (unsigned short)((u + 0x7FFFu + ((u >> 16) & 1u)) >> 16);
}
__device__ __forceinline__ float bflo(uint32_t x) { return __uint_as_float(x << 16); }
__device__ __forceinline__ float bfhi(uint32_t x) { return __uint_as_float(x & 0xFFFF0000u); }

// ---------- merged projection: l2norm(X @ W + b) in fp64; store bf16 + f32 residual.
// 32-row tiles, 512 threads: thread = 8 rows x 2 cols (r4's proven 8-row depth,
// half the cols). Grid 1024 x 8 waves -> 32 waves/CU cap (r4's 256-thr variant
// capped at 16 waves/CU = the measured 38% idle). Per-output FMA order is
// BIT-IDENTICAL to r4 (k ascending, single accumulator). Only the l2norm ss
// reduce order changes (2-col partials + cross-wave LDS add): ~1e-16 fp64
// perturbation, absorbed by the out-kernel band rescore.
// History: r4/r8/r10 (256thr, 4col) = 115.5us; r7 dbuf = 160-186us (LDS 2x ->
// occupancy half); r9 k-split (4 rows) = 126-131us (halved FMA/W-byte). This
// variant keeps FMA/W-byte and fixes the grid cap instead.
__global__ __launch_bounds__(512) void proj_kernel(
    const float* __restrict__ Xq, const float* __restrict__ Wq, const float* __restrict__ bq,
    const float* __restrict__ Xk, const float* __restrict__ Wk, const float* __restrict__ bk,
    unsigned short* __restrict__ Qb, float* __restrict__ Qlo,
    unsigned short* __restrict__ Kb, float* __restrict__ Klo)
{
  __shared__ double At[64][32];      // [k][row]; compute reads are wave-broadcast
  __shared__ double ssbuf[4][8][2];  // [rowgrp][row][wavehalf]
  const int tid = threadIdx.x;
  int blk = blockIdx.x;
  const float *X, *W, *bias; unsigned short* Pb; float* Plo;
  if (blk < 256) { X = Xq; W = Wq; bias = bq; Pb = Qb; Plo = Qlo; }
  else           { X = Xk; W = Wk; bias = bk; Pb = Kb; Plo = Klo; blk -= 256; }
  const int rbase = blk * 32;
  const int rowgrp = tid >> 7;       // 4 groups x 8 rows
  const int r0 = rowgrp * 8;
  const int c2 = (tid & 127) * 2;    // 2 cols per thread

  double acc[8][2];
  #pragma unroll
  for (int i = 0; i < 8; i++) {
    acc[i][0] = (double)bias[c2];
    acc[i][1] = (double)bias[c2 + 1];
  }

  const int srow = tid & 31, skq = (tid >> 5) * 4;   // 512 thr x float4 = 64k x 32 rows
  for (int kc = 0; kc < CH; kc += 64) {
    {
      const float4 v = *(const float4*)(X + (size_t)(rbase + srow) * CH + kc + skq);
      At[skq + 0][srow] = (double)v.x; At[skq + 1][srow] = (double)v.y;
      At[skq + 2][srow] = (double)v.z; At[skq + 3][srow] = (double)v.w;
    }
    __syncthreads();
    #pragma unroll 8
    for (int k = 0; k < 64; k++) {
      const float2 w2 = *(const float2*)(W + (size_t)(kc + k) * CH + c2);
      const double b0 = (double)w2.x, b1 = (double)w2.y;
      double a[8];
      #pragma unroll
      for (int i = 0; i < 4; i++) {
        const double2 ap = *(const double2*)&At[k][r0 + 2 * i];
        a[2*i] = ap.x; a[2*i+1] = ap.y;
      }
      #pragma unroll
      for (int i = 0; i < 8; i++) {
        acc[i][0] += a[i] * b0;
        acc[i][1] += a[i] * b1;
      }
    }
    __syncthreads();
  }

  // row sum-of-squares: wave tree over 64 colpairs, then combine the 2 waves
  // sharing this rowgrp via LDS (deterministic order: ssbuf[0] + ssbuf[1]).
  double ssw[8];
  #pragma unroll
  for (int i = 0; i < 8; i++) {
    double ss = acc[i][0] * acc[i][0] + acc[i][1] * acc[i][1];
    #pragma unroll
    for (int off = 32; off >= 1; off >>= 1) ss += __shfl_xor(ss, off);
    ssw[i] = ss;
  }
  const int wh = (tid >> 6) & 1;
  if ((tid & 63) == 0) {
    #pragma unroll
    for (int i = 0; i < 8; i++) ssbuf[rowgrp][i][wh] = ssw[i];
  }
  __syncthreads();

  #pragma unroll
  for (int i = 0; i < 8; i++) {
    const double inv = 1.0 / sqrt(ssbuf[rowgrp][i][0] + ssbuf[rowgrp][i][1] + 1e-12);
    const size_t base = (size_t)(rbase + r0 + i) * CH + c2;
    const double vd0 = acc[i][0] * inv;
    const double vd1 = acc[i][1] * inv;
    const unsigned short us0 = f2bf_rne((float)vd0);
    const unsigned short us1 = f2bf_rne((float)vd1);
    *(uint32_t*)(Pb + base) = (uint32_t)us0 | ((uint32_t)us1 << 16);
    float2 lo;
    lo.x = (float)(vd0 - (double)__uint_as_float(((uint32_t)us0) << 16));
    lo.y = (float)(vd1 - (double)__uint_as_float(((uint32_t)us1) << 16));
    *(float2*)(Plo + base) = lo;
  }
}

// ---------- sim (bf16 16x16x32 MFMA) + per-lane top-16 + 4-lane merge.
// Also emits the fp16 ref copy (4096 elems/block x 1536 blocks = exact cover):
// sim is VALU/MFMA-bound with idle VMEM, so the extra 38 MB streams for free.
// grid: bt(6) x qb(64) x rs(4); block 256 thr = 4 waves; wave = 16 q x 1024 r
// key = [22 value bits of (sim+2.0)][10-bit rloc]
__global__ __launch_bounds__(256, 4) void sim_cand_kernel(
    const unsigned short* __restrict__ Qb,
    const unsigned short* __restrict__ Kb,
    uint32_t* __restrict__ cand,
    const float* __restrict__ ref,
    unsigned short* __restrict__ ref16, int use16)
{
  __shared__ unsigned short kst[2][32 * 256];  // 2 x 16 KB, 16B-cols rotated by row
  const int bid = blockIdx.x;
  const int rs = bid & 3;
  const int qb = (bid >> 2) & 63;
  const int bt = bid >> 8;
  const int b = bt / T_FRAMES;
  const int tid = threadIdx.x;
  const int wv = tid >> 6, lane = tid & 63;
  const int lq = lane & 15, g = lane >> 4;
  const int q = qb * 64 + wv * 16 + lq;

  // fp16 ref copy: this block's 4096-element slice, coalesced 32B/lane reads
  if (use16) {
    #pragma unroll
    for (int pass = 0; pass < 2; pass++) {
      const size_t i = (size_t)bid * 4096 + (size_t)pass * 2048 + (size_t)tid * 8;
      const float4 v0 = *(const float4*)(ref + i);
      const float4 v1 = *(const float4*)(ref + i + 4);
      const uint32_t h0 = (uint32_t)__half_as_ushort(__float2half_rn(v0.x));
      const uint32_t h1 = (uint32_t)__half_as_ushort(__float2half_rn(v0.y));
      const uint32_t h2 = (uint32_t)__half_as_ushort(__float2half_rn(v0.z));
      const uint32_t h3 = (uint32_t)__half_as_ushort(__float2half_rn(v0.w));
      const uint32_t h4 = (uint32_t)__half_as_ushort(__float2half_rn(v1.x));
      const uint32_t h5 = (uint32_t)__half_as_ushort(__float2half_rn(v1.y));
      const uint32_t h6 = (uint32_t)__half_as_ushort(__float2half_rn(v1.z));
      const uint32_t h7 = (uint32_t)__half_as_ushort(__float2half_rn(v1.w));
      uint4 hv;
      hv.x = h0 | (h1 << 16); hv.y = h2 | (h3 << 16);
      hv.z = h4 | (h5 << 16); hv.w = h6 | (h7 << 16);
      *(uint4*)(ref16 + i) = hv;
    }
  }

  bf16x8 bfr[8];
  {
    const unsigned short* qrow = Qb + (size_t)(b * NTOK + q) * CH + g * 8;
    #pragma unroll
    for (int kc = 0; kc < 8; kc++) bfr[kc] = *(const bf16x8*)(qrow + kc * 32);
  }
  uint32_t best[16];
  #pragma unroll
  for (int i = 0; i < 16; i++) best[i] = 0u;
  uint32_t s[16];

  const unsigned short* kbase = Kb + ((size_t)bt * NTOK + (size_t)rs * 1024) * CH;

#define STAGE(C, BUFI)                                                          \
  {                                                                             \
    _Pragma("unroll")                                                           \
    for (int t = 0; t < 4; t++) {                                               \
      const int o16 = (wv * 4 + t) * 64 + lane;                                 \
      const int row = o16 >> 5, colp = o16 & 31;                                \
      const int col16 = (colp - row) & 31;                                      \
      const unsigned short* gsrc = kbase + (size_t)((C) * 32 + row) * CH + col16 * 8; \
      __builtin_amdgcn_global_load_lds((const gvoid*)gsrc,                      \
          (svoid*)(&kst[BUFI][0] + (size_t)(wv * 4 + t) * 512), 16, 0, 0);      \
    }                                                                           \
  }

#define COMPUTE_HALF(CBASE, BUFI, SOFF)                                         \
  {                                                                             \
    _Pragma("unroll")                                                           \
    for (int t = 0; t < 2; t++) {                                               \
      f32x4 acc = {2.0f, 2.0f, 2.0f, 2.0f};                                     \
      const int arow = t * 16 + lq;                                             \
      const unsigned short* rowp = &kst[BUFI][0] + (size_t)arow * 256;          \
      _Pragma("unroll")                                                         \
      for (int kc = 0; kc < 8; kc++) {                                          \
        const int colp = (kc * 4 + g + arow) & 31;                              \
        const bf16x8 a = *(const bf16x8*)(rowp + colp * 8);                     \
        acc = __builtin_amdgcn_mfma_f32_16x16x32_bf16(a, bfr[kc], acc, 0, 0, 0);\
      }                                                                         \
      _Pragma("unroll")                                                         \
      for (int j = 0; j < 4; j++) {                                             \
        const uint32_t bits = __float_as_uint(acc[j]);                          \
        s[(SOFF) + t * 4 + j] = (bits & 0xFFFFFC00u) |                          \
            (uint32_t)((CBASE) * 32 + t * 16 + g * 4 + j);                      \
      }                                                                         \
    }                                                                           \
  }

#define SORT16_MERGE()                                                          \
  {                                                                             \
    _Pragma("unroll")                                                           \
    for (int bk = 2; bk <= 16; bk <<= 1) {                                      \
      _Pragma("unroll")                                                         \
      for (int bj = bk >> 1; bj > 0; bj >>= 1) {                                \
        _Pragma("unroll")                                                       \
        for (int i = 0; i < 16; i++) {                                          \
          const int l = i ^ bj;                                                 \
          if (l > i) {                                                          \
            const bool up = ((i & bk) != 0);                                    \
            const uint32_t a2 = s[i], b2 = s[l];                                \
            const uint32_t mn = a2 < b2 ? a2 : b2;                              \
            const uint32_t mx = a2 < b2 ? b2 : a2;                              \
            s[i] = up ? mn : mx; s[l] = up ? mx : mn;                           \
          }                                                                     \
        }                                                                       \
      }                                                                         \
    }                                                                           \
    uint32_t m[16];                                                             \
    _Pragma("unroll")                                                           \
    for (int i = 0; i < 16; i++) {                                              \
      const uint32_t a2 = best[i], b2 = s[15 - i];                              \
      m[i] = a2 > b2 ? a2 : b2;                                                 \
    }                                                                           \
    _Pragma("unroll")                                                           \
    for (int bj = 8; bj > 0; bj >>= 1) {                                        \
      _Pragma("unroll")                                                         \
      for (int i = 0; i < 16; i++) {                                            \
        const int l = i ^ bj;                                                   \
        if (l > i) {                                                            \
          const uint32_t a2 = m[i], b2 = m[l];                                  \
          const uint32_t mn = a2 < b2 ? a2 : b2;                                \
          const uint32_t mx = a2 < b2 ? b2 : a2;                                \
          m[i] = mx; m[l] = mn;                                                 \
        }                                                                       \
      }                                                                         \
    }                                                                           \
    _Pragma("unroll")                                                           \
    for (int i = 0; i < 16; i++) best[i] = m[i];                                \
  }

  STAGE(0, 0);
  __syncthreads();
  for (int cp = 0; cp < 16; cp++) {
    const int c0 = 2 * cp;
    STAGE(c0 + 1, 1);
    COMPUTE_HALF(c0, 0, 0);
    __syncthreads();
    if (cp < 15) STAGE(c0 + 2, 0);
    COMPUTE_HALF(c0 + 1, 1, 8);
    SORT16_MERGE();
    __syncthreads();
  }

  #pragma unroll
  for (int st = 16; st <= 32; st <<= 1) {
    uint32_t o[16];
    #pragma unroll
    for (int i = 0; i < 16; i++) o[i] = (uint32_t)__shfl_xor((int)best[15 - i], st);
    #pragma unroll
    for (int i = 0; i < 16; i++) best[i] = best[i] > o[i] ? best[i] : o[i];
    #pragma unroll
    for (int bj = 8; bj > 0; bj >>= 1) {
      #pragma unroll
      for (int i = 0; i < 16; i++) {
        const int l = i ^ bj;
        if (l > i) {
          const uint32_t a2 = best[i], b2 = best[l];
          const uint32_t mn = a2 < b2 ? a2 : b2;
          const uint32_t mx = a2 < b2 ? b2 : a2;
          best[i] = mx; best[l] = mn;
        }
      }
    }
  }
  if (g == 0) {
    uint32_t* cp2 = cand + ((size_t)bt * NTOK + q) * 64 + rs * 16;
    #pragma unroll
    for (int i = 0; i < 16; i += 4) {
      uint4 v; v.x = best[i]; v.y = best[i+1]; v.z = best[i+2]; v.w = best[i+3];
      *(uint4*)(cp2 + i) = v;
    }
  }
#undef STAGE
#undef COMPUTE_HALF
#undef SORT16_MERGE
}

// ---------- final: sort 64 cands, fp64 band rescore (exact SET), softmax on
// mixed exact/coarse values, gather (fp16 copy when available).
// XCD-chunked swizzle keeps each XCD's gather working set L2-warm.
// BW = 2.5e-3: coarse-key error bound = quant 2.4e-4 + bf16 dot noise ~6e-4
// => E<=8.4e-4; band must exceed 2E=1.7e-3; 2.5e-3 keeps 1.5x margin.
__global__ __launch_bounds__(256) void out_kernel(
    const unsigned short* __restrict__ Qb, const float* __restrict__ Qlo,
    const unsigned short* __restrict__ Kb, const float* __restrict__ Klo,
    const uint32_t* __restrict__ cand, const float* __restrict__ ref,
    const unsigned short* __restrict__ ref16, int use16,
    float* __restrict__ out)
{
  const int tid = threadIdx.x, wv = tid >> 6, lane = tid & 63;
  const int bid = blockIdx.x;
  const int work = (bid & 7) * 768 + (bid >> 3);   // bijective, 6144 blocks
  const int rowid = work * 4 + wv;
  const int bt = rowid >> 12, q = rowid & 4095;
  const int b = bt / T_FRAMES;

  const uint32_t k0 = cand[(size_t)rowid * 64 + lane];
  uint32_t key = (k0 & 0xFFFFF000u) | ((uint32_t)(lane >> 4) << 10) | (k0 & 0x3FFu);

  // ascending bitonic-64, keys only (global r embedded in low 12 bits)
  #pragma unroll
  for (int k = 2; k <= 64; k <<= 1) {
    #pragma unroll
    for (int j = k >> 1; j > 0; j >>= 1) {
      const uint32_t ok = (uint32_t)__shfl_xor((int)key, j);
      const bool takeMax = (((lane & j) != 0) == ((lane & k) == 0));
      if ((ok > key) == takeMax) key = ok;
    }
  }
  const float v = __uint_as_float(key & 0xFFFFF000u) - 2.0f;
  int rr = (int)(key & 0xFFFu);

  const float v16c = __shfl(v, 48);
  const float BW = 2.5e-3f;
  const bool band = fabsf(v - v16c) <= BW;

  // reconstruct q channels lane*4..+3 in fp64
  const uint2 qbv = *(const uint2*)(Qb + (size_t)(b * NTOK + q) * CH + lane * 4);
  const float4 qlv = *(const float4*)(Qlo + (size_t)(b * NTOK + q) * CH + lane * 4);
  const double qd0 = (double)bflo(qbv.x) + (double)qlv.x;
  const double qd1 = (double)bfhi(qbv.x) + (double)qlv.y;
  const double qd2 = (double)bflo(qbv.y) + (double)qlv.z;
  const double qd3 = (double)bfhi(qbv.y) + (double)qlv.w;

  const unsigned short* kbp = Kb + (size_t)bt * NTOK * CH;
  const float* klp = Klo + (size_t)bt * NTOK * CH;

  double dval = -1.0e300;
  {
    const unsigned long long bm = __ballot(band);
    const int lo = __ffsll(bm) - 1;
    const int hi = 63 - __clzll(bm);
    for (int idx = lo; idx <= hi; idx++) {
      const int ri = __shfl(rr, idx);
      const uint2 kbv = *(const uint2*)(kbp + (size_t)ri * CH + lane * 4);
      const float4 klv = *(const float4*)(klp + (size_t)ri * CH + lane * 4);
      double dd = qd0 * ((double)bflo(kbv.x) + (double)klv.x)
                + qd1 * ((double)bfhi(kbv.x) + (double)klv.y)
                + qd2 * ((double)bflo(kbv.y) + (double)klv.z)
                + qd3 * ((double)bfhi(kbv.y) + (double)klv.w);
      #pragma unroll
      for (int off = 32; off >= 1; off >>= 1) dd += __shfl_xor(dd, off);
      if (lane == idx) dval = dd;
    }
  }
  double p = band ? dval : ((v > v16c + BW) ? (double)v : -1.0e300);

  // ascending bitonic on (p, rr): top-16 land in lanes 48..63.
  #pragma unroll
  for (int k = 2; k <= 64; k <<= 1) {
    #pragma unroll
    for (int j = k >> 1; j > 0; j >>= 1) {
      const double op = __shfl_xor(p, j);
      const int orr = __shfl_xor(rr, j);
      const bool takeMax = (((lane & j) != 0) == ((lane & k) == 0));
      const bool og = (op > p) || (op == p && orr < rr);
      if (takeMax == og) { p = op; rr = orr; }
    }
  }

  // softmax over lanes 48..63
  double pm = p;
  #pragma unroll
  for (int j = 8; j >= 1; j >>= 1) pm = fmax(pm, __shfl_xor(pm, j));
  double e = (lane >= 48) ? exp(p - pm) : 0.0;
  double es = e;
  #pragma unroll
  for (int j = 8; j >= 1; j >>= 1) es += __shfl_xor(es, j);
  const float w = (float)(e / es);

  float a0 = 0.f, a1 = 0.f, a2 = 0.f, a3 = 0.f;
  if (use16) {
    const unsigned short* rb16 = ref16 + (size_t)bt * NTOK * CH + lane * 4;
    #pragma unroll
    for (int i = 0; i < 16; i++) {
      const float wi = __shfl(w, 48 + i);
      const int ri = __shfl(rr, 48 + i) & 0xFFF;
      const uint2 hv = *(const uint2*)(rb16 + (size_t)ri * CH);
      a0 += wi * __half2float(__ushort_as_half((unsigned short)(hv.x & 0xFFFFu)));
      a1 += wi * __half2float(__ushort_as_half((unsigned short)(hv.x >> 16)));
      a2 += wi * __half2float(__ushort_as_half((unsigned short)(hv.y & 0xFFFFu)));
      a3 += wi * __half2float(__ushort_as_half((unsigned short)(hv.y >> 16)));
    }
  } else {
    const float* rbp = ref + (size_t)bt * NTOK * CH + lane * 4;
    #pragma unroll
    for (int i = 0; i < 16; i++) {
      const float wi = __shfl(w, 48 + i);
      const int ri = __shfl(rr, 48 + i) & 0xFFF;
      const float4 f = *(const float4*)(rbp + (size_t)ri * CH);
      a0 += wi * f.x; a1 += wi * f.y; a2 += wi * f.z; a3 += wi * f.w;
    }
  }
  float4 o; o.x = a0; o.y = a1; o.z = a2; o.w = a3;
  *(float4*)(out + (size_t)rowid * CH + lane * 4) = o;
}

extern "C" void kernel_launch(void* const* d_in, const int* in_sizes, int n_in,
                              void* d_out, int out_size, void* d_ws, size_t ws_size,
                              hipStream_t stream) {
  const float* tgt = (const float*)d_in[0];
  const float* ref = (const float*)d_in[1];
  const float* Wq  = (const float*)d_in[2];
  const float* bq  = (const float*)d_in[3];
  const float* Wk  = (const float*)d_in[4];
  const float* bk  = (const float*)d_in[5];
  float* out = (float*)d_out;

  const int B = 2;
  const int RQ = B * NTOK;            // 8192
  const int RK = B * T_FRAMES * NTOK; // 24576

  char* ws = (char*)d_ws;
  unsigned short* Qb = (unsigned short*)ws; ws += (size_t)RQ * CH * 2;  // 4.19 MB
  float* Qlo = (float*)ws;                  ws += (size_t)RQ * CH * 4;  // 8.39 MB
  unsigned short* Kb = (unsigned short*)ws; ws += (size_t)RK * CH * 2;  // 12.58 MB
  float* Klo = (float*)ws;                  ws += (size_t)RK * CH * 4;  // 25.17 MB
  uint32_t* cand = (uint32_t*)ws;           ws += (size_t)RK * 64 * 4;  // 6.29 MB
  // base total = 56,623,104 B (known safe); optional ref16 = +12,582,912 B
  const bool big = ws_size >= (size_t)69206016;
  unsigned short* ref16 = big ? (unsigned short*)ws : nullptr;
  const int use16 = big ? 1 : 0;

  proj_kernel<<<RQ / 32 + RK / 32, 512, 0, stream>>>(
      tgt, Wq, bq, ref, Wk, bk, Qb, Qlo, Kb, Klo);
  sim_cand_kernel<<<6 * 64 * 4, 256, 0, stream>>>(Qb, Kb, cand, ref, ref16, use16);
  out_kernel<<<RK / 4, 256, 0, stream>>>(Qb, Qlo, Kb, Klo, cand, ref, ref16, use16, out);
}

// Round 12
// 250.180 us; speedup vs baseline: 1.0633x; 1.0633x over previous
//
#include <hip/hip_runtime.h>
#include <hip/hip_fp16.h>
#include <stdint.h>

#define T_FRAMES 3
#define NTOK 4096
#define CH 256

typedef __attribute__((ext_vector_type(8))) short bf16x8;
typedef __attribute__((ext_vector_type(4))) float f32x4;
typedef __attribute__((address_space(1))) void gvoid;
typedef __attribute__((address_space(3))) void svoid;

__device__ __forceinline__ unsigned short f2bf_rne(float f) {
  union { float f; uint32_t u; } c; c.f = f;
  uint32_t u = c.u;
  return (unsigned short)((u + 0x7FFFu + ((u >> 16) & 1u)) >> 16);
}
__device__ __forceinline__ float bflo(uint32_t x) { return __uint_as_float(x << 16); }
__device__ __forceinline__ float bfhi(uint32_t x) { return __uint_as_float(x & 0xFFFF0000u); }

// ---------- merged projection: l2norm(X @ W + b) in fp64; store bf16 + f32 residual
// EXACT round-4/8/10 version — measured optimum 115.5 +/- 1 us across 3 rounds.
// 32-row tiles, 256 thr: thread = 8 rows x 4 cols; wave = 8 rows, lanes span cols.
// FAILED alternatives (do not re-attempt):
//   r7  double-buffer:  160-186us (2x LDS -> occupancy halved, TLP was binding)
//   r9  k-split 4-row:  126-131us (halved FMA per W-load)
//   r11 col-split 8x2:  133-141us (halved FMA per LDS-broadcast-read)
// Structure: busy ~71us (55 fp64-FMA floor + 16 cvt/addr/stage), ~45us
// barrier/latency at 16 waves/CU. This balance point is the local optimum.
__global__ __launch_bounds__(256) void proj_kernel(
    const float* __restrict__ Xq, const float* __restrict__ Wq, const float* __restrict__ bq,
    const float* __restrict__ Xk, const float* __restrict__ Wk, const float* __restrict__ bk,
    unsigned short* __restrict__ Qb, float* __restrict__ Qlo,
    unsigned short* __restrict__ Kb, float* __restrict__ Klo)
{
  __shared__ double At[64][32];   // [k][row]; inner-loop reads are wave-broadcast
  const int tid = threadIdx.x;
  int blk = blockIdx.x;
  const float *X, *W, *bias; unsigned short* Pb; float* Plo;
  if (blk < 256) { X = Xq; W = Wq; bias = bq; Pb = Qb; Plo = Qlo; }
  else           { X = Xk; W = Wk; bias = bk; Pb = Kb; Plo = Klo; blk -= 256; }
  const int rbase = blk * 32;
  const int wv = tid >> 6, lane = tid & 63;
  const int r0 = wv * 8;
  const int c4 = lane * 4;

  double acc[8][4];
  #pragma unroll
  for (int i = 0; i < 8; i++) {
    #pragma unroll
    for (int j = 0; j < 4; j++) acc[i][j] = (double)bias[c4 + j];
  }

  const int srow = tid & 31, skq = (tid >> 5) * 8;
  for (int kc = 0; kc < CH; kc += 64) {
    {
      const float* xp = X + (size_t)(rbase + srow) * CH + kc + skq;
      const float4 v0 = *(const float4*)(xp);
      const float4 v1 = *(const float4*)(xp + 4);
      At[skq + 0][srow] = (double)v0.x; At[skq + 1][srow] = (double)v0.y;
      At[skq + 2][srow] = (double)v0.z; At[skq + 3][srow] = (double)v0.w;
      At[skq + 4][srow] = (double)v1.x; At[skq + 5][srow] = (double)v1.y;
      At[skq + 6][srow] = (double)v1.z; At[skq + 7][srow] = (double)v1.w;
    }
    __syncthreads();
    #pragma unroll 8
    for (int k = 0; k < 64; k++) {
      const float4 w4 = *(const float4*)(W + (size_t)(kc + k) * CH + c4);
      const double b0 = (double)w4.x, b1 = (double)w4.y;
      const double b2 = (double)w4.z, b3 = (double)w4.w;
      double a[8];
      #pragma unroll
      for (int i = 0; i < 4; i++) {
        const double2 ap = *(const double2*)&At[k][r0 + 2 * i];
        a[2*i] = ap.x; a[2*i+1] = ap.y;
      }
      #pragma unroll
      for (int i = 0; i < 8; i++) {
        acc[i][0] += a[i] * b0; acc[i][1] += a[i] * b1;
        acc[i][2] += a[i] * b2; acc[i][3] += a[i] * b3;
      }
    }
    __syncthreads();
  }

  #pragma unroll
  for (int i = 0; i < 8; i++) {
    double ss = acc[i][0]*acc[i][0] + acc[i][1]*acc[i][1]
              + acc[i][2]*acc[i][2] + acc[i][3]*acc[i][3];
    #pragma unroll
    for (int off = 32; off >= 1; off >>= 1) ss += __shfl_xor(ss, off);
    const double inv = 1.0 / sqrt(ss + 1e-12);
    const size_t base = (size_t)(rbase + r0 + i) * CH + c4;
    double vd[4]; float fb[4]; unsigned short us[4];
    #pragma unroll
    for (int j = 0; j < 4; j++) {
      vd[j] = acc[i][j] * inv;
      us[j] = f2bf_rne((float)vd[j]);
      fb[j] = __uint_as_float(((uint32_t)us[j]) << 16);
    }
    uint2 pk; pk.x = (uint32_t)us[0] | ((uint32_t)us[1] << 16);
    pk.y = (uint32_t)us[2] | ((uint32_t)us[3] << 16);
    *(uint2*)(Pb + base) = pk;
    float4 lo;
    lo.x = (float)(vd[0] - (double)fb[0]); lo.y = (float)(vd[1] - (double)fb[1]);
    lo.z = (float)(vd[2] - (double)fb[2]); lo.w = (float)(vd[3] - (double)fb[3]);
    *(float4*)(Plo + base) = lo;
  }
}

// ---------- sim (bf16 16x16x32 MFMA) + per-lane top-16 + 4-lane merge.
// Also emits the fp16 ref copy (4096 elems/block x 1536 blocks = exact cover):
// sim is VALU/MFMA-bound with idle VMEM, so the extra 38 MB streams for free.
// grid: bt(6) x qb(64) x rs(4); block 256 thr = 4 waves; wave = 16 q x 1024 r
// key = [22 value bits of (sim+2.0)][10-bit rloc]
__global__ __launch_bounds__(256, 4) void sim_cand_kernel(
    const unsigned short* __restrict__ Qb,
    const unsigned short* __restrict__ Kb,
    uint32_t* __restrict__ cand,
    const float* __restrict__ ref,
    unsigned short* __restrict__ ref16, int use16)
{
  __shared__ unsigned short kst[2][32 * 256];  // 2 x 16 KB, 16B-cols rotated by row
  const int bid = blockIdx.x;
  const int rs = bid & 3;
  const int qb = (bid >> 2) & 63;
  const int bt = bid >> 8;
  const int b = bt / T_FRAMES;
  const int tid = threadIdx.x;
  const int wv = tid >> 6, lane = tid & 63;
  const int lq = lane & 15, g = lane >> 4;
  const int q = qb * 64 + wv * 16 + lq;

  // fp16 ref copy: this block's 4096-element slice, coalesced 32B/lane reads
  if (use16) {
    #pragma unroll
    for (int pass = 0; pass < 2; pass++) {
      const size_t i = (size_t)bid * 4096 + (size_t)pass * 2048 + (size_t)tid * 8;
      const float4 v0 = *(const float4*)(ref + i);
      const float4 v1 = *(const float4*)(ref + i + 4);
      const uint32_t h0 = (uint32_t)__half_as_ushort(__float2half_rn(v0.x));
      const uint32_t h1 = (uint32_t)__half_as_ushort(__float2half_rn(v0.y));
      const uint32_t h2 = (uint32_t)__half_as_ushort(__float2half_rn(v0.z));
      const uint32_t h3 = (uint32_t)__half_as_ushort(__float2half_rn(v0.w));
      const uint32_t h4 = (uint32_t)__half_as_ushort(__float2half_rn(v1.x));
      const uint32_t h5 = (uint32_t)__half_as_ushort(__float2half_rn(v1.y));
      const uint32_t h6 = (uint32_t)__half_as_ushort(__float2half_rn(v1.z));
      const uint32_t h7 = (uint32_t)__half_as_ushort(__float2half_rn(v1.w));
      uint4 hv;
      hv.x = h0 | (h1 << 16); hv.y = h2 | (h3 << 16);
      hv.z = h4 | (h5 << 16); hv.w = h6 | (h7 << 16);
      *(uint4*)(ref16 + i) = hv;
    }
  }

  bf16x8 bfr[8];
  {
    const unsigned short* qrow = Qb + (size_t)(b * NTOK + q) * CH + g * 8;
    #pragma unroll
    for (int kc = 0; kc < 8; kc++) bfr[kc] = *(const bf16x8*)(qrow + kc * 32);
  }
  uint32_t best[16];
  #pragma unroll
  for (int i = 0; i < 16; i++) best[i] = 0u;
  uint32_t s[16];

  const unsigned short* kbase = Kb + ((size_t)bt * NTOK + (size_t)rs * 1024) * CH;

#define STAGE(C, BUFI)                                                          \
  {                                                                             \
    _Pragma("unroll")                                                           \
    for (int t = 0; t < 4; t++) {                                               \
      const int o16 = (wv * 4 + t) * 64 + lane;                                 \
      const int row = o16 >> 5, colp = o16 & 31;                                \
      const int col16 = (colp - row) & 31;                                      \
      const unsigned short* gsrc = kbase + (size_t)((C) * 32 + row) * CH + col16 * 8; \
      __builtin_amdgcn_global_load_lds((const gvoid*)gsrc,                      \
          (svoid*)(&kst[BUFI][0] + (size_t)(wv * 4 + t) * 512), 16, 0, 0);      \
    }                                                                           \
  }

#define COMPUTE_HALF(CBASE, BUFI, SOFF)                                         \
  {                                                                             \
    _Pragma("unroll")                                                           \
    for (int t = 0; t < 2; t++) {                                               \
      f32x4 acc = {2.0f, 2.0f, 2.0f, 2.0f};                                     \
      const int arow = t * 16 + lq;                                             \
      const unsigned short* rowp = &kst[BUFI][0] + (size_t)arow * 256;          \
      _Pragma("unroll")                                                         \
      for (int kc = 0; kc < 8; kc++) {                                          \
        const int colp = (kc * 4 + g + arow) & 31;                              \
        const bf16x8 a = *(const bf16x8*)(rowp + colp * 8);                     \
        acc = __builtin_amdgcn_mfma_f32_16x16x32_bf16(a, bfr[kc], acc, 0, 0, 0);\
      }                                                                         \
      _Pragma("unroll")                                                         \
      for (int j = 0; j < 4; j++) {                                             \
        const uint32_t bits = __float_as_uint(acc[j]);                          \
        s[(SOFF) + t * 4 + j] = (bits & 0xFFFFFC00u) |                          \
            (uint32_t)((CBASE) * 32 + t * 16 + g * 4 + j);                      \
      }                                                                         \
    }                                                                           \
  }

#define SORT16_MERGE()                                                          \
  {                                                                             \
    _Pragma("unroll")                                                           \
    for (int bk = 2; bk <= 16; bk <<= 1) {                                      \
      _Pragma("unroll")                                                         \
      for (int bj = bk >> 1; bj > 0; bj >>= 1) {                                \
        _Pragma("unroll")                                                       \
        for (int i = 0; i < 16; i++) {                                          \
          const int l = i ^ bj;                                                 \
          if (l > i) {                                                          \
            const bool up = ((i & bk) != 0);                                    \
            const uint32_t a2 = s[i], b2 = s[l];                                \
            const uint32_t mn = a2 < b2 ? a2 : b2;                              \
            const uint32_t mx = a2 < b2 ? b2 : a2;                              \
            s[i] = up ? mn : mx; s[l] = up ? mx : mn;                           \
          }                                                                     \
        }                                                                       \
      }                                                                         \
    }                                                                           \
    uint32_t m[16];                                                             \
    _Pragma("unroll")                                                           \
    for (int i = 0; i < 16; i++) {                                              \
      const uint32_t a2 = best[i], b2 = s[15 - i];                              \
      m[i] = a2 > b2 ? a2 : b2;                                                 \
    }                                                                           \
    _Pragma("unroll")                                                           \
    for (int bj = 8; bj > 0; bj >>= 1) {                                        \
      _Pragma("unroll")                                                         \
      for (int i = 0; i < 16; i++) {                                            \
        const int l = i ^ bj;                                                   \
        if (l > i) {                                                            \
          const uint32_t a2 = m[i], b2 = m[l];                                  \
          const uint32_t mn = a2 < b2 ? a2 : b2;                                \
          const uint32_t mx = a2 < b2 ? b2 : a2;                                \
          m[i] = mx; m[l] = mn;                                                 \
        }                                                                       \
      }                                                                         \
    }                                                                           \
    _Pragma("unroll")                                                           \
    for (int i = 0; i < 16; i++) best[i] = m[i];                                \
  }

  STAGE(0, 0);
  __syncthreads();
  for (int cp = 0; cp < 16; cp++) {
    const int c0 = 2 * cp;
    STAGE(c0 + 1, 1);
    COMPUTE_HALF(c0, 0, 0);
    __syncthreads();
    if (cp < 15) STAGE(c0 + 2, 0);
    COMPUTE_HALF(c0 + 1, 1, 8);
    SORT16_MERGE();
    __syncthreads();
  }

  #pragma unroll
  for (int st = 16; st <= 32; st <<= 1) {
    uint32_t o[16];
    #pragma unroll
    for (int i = 0; i < 16; i++) o[i] = (uint32_t)__shfl_xor((int)best[15 - i], st);
    #pragma unroll
    for (int i = 0; i < 16; i++) best[i] = best[i] > o[i] ? best[i] : o[i];
    #pragma unroll
    for (int bj = 8; bj > 0; bj >>= 1) {
      #pragma unroll
      for (int i = 0; i < 16; i++) {
        const int l = i ^ bj;
        if (l > i) {
          const uint32_t a2 = best[i], b2 = best[l];
          const uint32_t mn = a2 < b2 ? a2 : b2;
          const uint32_t mx = a2 < b2 ? b2 : a2;
          best[i] = mx; best[l] = mn;
        }
      }
    }
  }
  if (g == 0) {
    uint32_t* cp2 = cand + ((size_t)bt * NTOK + q) * 64 + rs * 16;
    #pragma unroll
    for (int i = 0; i < 16; i += 4) {
      uint4 v; v.x = best[i]; v.y = best[i+1]; v.z = best[i+2]; v.w = best[i+3];
      *(uint4*)(cp2 + i) = v;
    }
  }
#undef STAGE
#undef COMPUTE_HALF
#undef SORT16_MERGE
}

// ---------- final: sort 64 cands, fp64 band rescore (exact SET), softmax on
// mixed exact/coarse values, gather (fp16 copy when available).
// XCD-chunked swizzle keeps each XCD's gather working set L2-warm.
// BW = 2.5e-3: coarse-key error bound = quant 2.4e-4 + bf16 dot noise ~6e-4
// => E<=8.4e-4; band must exceed 2E=1.7e-3; 2.5e-3 keeps 1.5x margin.
__global__ __launch_bounds__(256) void out_kernel(
    const unsigned short* __restrict__ Qb, const float* __restrict__ Qlo,
    const unsigned short* __restrict__ Kb, const float* __restrict__ Klo,
    const uint32_t* __restrict__ cand, const float* __restrict__ ref,
    const unsigned short* __restrict__ ref16, int use16,
    float* __restrict__ out)
{
  const int tid = threadIdx.x, wv = tid >> 6, lane = tid & 63;
  const int bid = blockIdx.x;
  const int work = (bid & 7) * 768 + (bid >> 3);   // bijective, 6144 blocks
  const int rowid = work * 4 + wv;
  const int bt = rowid >> 12, q = rowid & 4095;
  const int b = bt / T_FRAMES;

  const uint32_t k0 = cand[(size_t)rowid * 64 + lane];
  uint32_t key = (k0 & 0xFFFFF000u) | ((uint32_t)(lane >> 4) << 10) | (k0 & 0x3FFu);

  // ascending bitonic-64, keys only (global r embedded in low 12 bits)
  #pragma unroll
  for (int k = 2; k <= 64; k <<= 1) {
    #pragma unroll
    for (int j = k >> 1; j > 0; j >>= 1) {
      const uint32_t ok = (uint32_t)__shfl_xor((int)key, j);
      const bool takeMax = (((lane & j) != 0) == ((lane & k) == 0));
      if ((ok > key) == takeMax) key = ok;
    }
  }
  const float v = __uint_as_float(key & 0xFFFFF000u) - 2.0f;
  int rr = (int)(key & 0xFFFu);

  const float v16c = __shfl(v, 48);
  const float BW = 2.5e-3f;
  const bool band = fabsf(v - v16c) <= BW;

  // reconstruct q channels lane*4..+3 in fp64
  const uint2 qbv = *(const uint2*)(Qb + (size_t)(b * NTOK + q) * CH + lane * 4);
  const float4 qlv = *(const float4*)(Qlo + (size_t)(b * NTOK + q) * CH + lane * 4);
  const double qd0 = (double)bflo(qbv.x) + (double)qlv.x;
  const double qd1 = (double)bfhi(qbv.x) + (double)qlv.y;
  const double qd2 = (double)bflo(qbv.y) + (double)qlv.z;
  const double qd3 = (double)bfhi(qbv.y) + (double)qlv.w;

  const unsigned short* kbp = Kb + (size_t)bt * NTOK * CH;
  const float* klp = Klo + (size_t)bt * NTOK * CH;

  double dval = -1.0e300;
  {
    const unsigned long long bm = __ballot(band);
    const int lo = __ffsll(bm) - 1;
    const int hi = 63 - __clzll(bm);
    for (int idx = lo; idx <= hi; idx++) {
      const int ri = __shfl(rr, idx);
      const uint2 kbv = *(const uint2*)(kbp + (size_t)ri * CH + lane * 4);
      const float4 klv = *(const float4*)(klp + (size_t)ri * CH + lane * 4);
      double dd = qd0 * ((double)bflo(kbv.x) + (double)klv.x)
                + qd1 * ((double)bfhi(kbv.x) + (double)klv.y)
                + qd2 * ((double)bflo(kbv.y) + (double)klv.z)
                + qd3 * ((double)bfhi(kbv.y) + (double)klv.w);
      #pragma unroll
      for (int off = 32; off >= 1; off >>= 1) dd += __shfl_xor(dd, off);
      if (lane == idx) dval = dd;
    }
  }
  double p = band ? dval : ((v > v16c + BW) ? (double)v : -1.0e300);

  // ascending bitonic on (p, rr): top-16 land in lanes 48..63.
  #pragma unroll
  for (int k = 2; k <= 64; k <<= 1) {
    #pragma unroll
    for (int j = k >> 1; j > 0; j >>= 1) {
      const double op = __shfl_xor(p, j);
      const int orr = __shfl_xor(rr, j);
      const bool takeMax = (((lane & j) != 0) == ((lane & k) == 0));
      const bool og = (op > p) || (op == p && orr < rr);
      if (takeMax == og) { p = op; rr = orr; }
    }
  }

  // softmax over lanes 48..63
  double pm = p;
  #pragma unroll
  for (int j = 8; j >= 1; j >>= 1) pm = fmax(pm, __shfl_xor(pm, j));
  double e = (lane >= 48) ? exp(p - pm) : 0.0;
  double es = e;
  #pragma unroll
  for (int j = 8; j >= 1; j >>= 1) es += __shfl_xor(es, j);
  const float w = (float)(e / es);

  float a0 = 0.f, a1 = 0.f, a2 = 0.f, a3 = 0.f;
  if (use16) {
    const unsigned short* rb16 = ref16 + (size_t)bt * NTOK * CH + lane * 4;
    #pragma unroll
    for (int i = 0; i < 16; i++) {
      const float wi = __shfl(w, 48 + i);
      const int ri = __shfl(rr, 48 + i) & 0xFFF;
      const uint2 hv = *(const uint2*)(rb16 + (size_t)ri * CH);
      a0 += wi * __half2float(__ushort_as_half((unsigned short)(hv.x & 0xFFFFu)));
      a1 += wi * __half2float(__ushort_as_half((unsigned short)(hv.x >> 16)));
      a2 += wi * __half2float(__ushort_as_half((unsigned short)(hv.y & 0xFFFFu)));
      a3 += wi * __half2float(__ushort_as_half((unsigned short)(hv.y >> 16)));
    }
  } else {
    const float* rbp = ref + (size_t)bt * NTOK * CH + lane * 4;
    #pragma unroll
    for (int i = 0; i < 16; i++) {
      const float wi = __shfl(w, 48 + i);
      const int ri = __shfl(rr, 48 + i) & 0xFFF;
      const float4 f = *(const float4*)(rbp + (size_t)ri * CH);
      a0 += wi * f.x; a1 += wi * f.y; a2 += wi * f.z; a3 += wi * f.w;
    }
  }
  float4 o; o.x = a0; o.y = a1; o.z = a2; o.w = a3;
  *(float4*)(out + (size_t)rowid * CH + lane * 4) = o;
}

extern "C" void kernel_launch(void* const* d_in, const int* in_sizes, int n_in,
                              void* d_out, int out_size, void* d_ws, size_t ws_size,
                              hipStream_t stream) {
  const float* tgt = (const float*)d_in[0];
  const float* ref = (const float*)d_in[1];
  const float* Wq  = (const float*)d_in[2];
  const float* bq  = (const float*)d_in[3];
  const float* Wk  = (const float*)d_in[4];
  const float* bk  = (const float*)d_in[5];
  float* out = (float*)d_out;

  const int B = 2;
  const int RQ = B * NTOK;            // 8192
  const int RK = B * T_FRAMES * NTOK; // 24576

  char* ws = (char*)d_ws;
  unsigned short* Qb = (unsigned short*)ws; ws += (size_t)RQ * CH * 2;  // 4.19 MB
  float* Qlo = (float*)ws;                  ws += (size_t)RQ * CH * 4;  // 8.39 MB
  unsigned short* Kb = (unsigned short*)ws; ws += (size_t)RK * CH * 2;  // 12.58 MB
  float* Klo = (float*)ws;                  ws += (size_t)RK * CH * 4;  // 25.17 MB
  uint32_t* cand = (uint32_t*)ws;           ws += (size_t)RK * 64 * 4;  // 6.29 MB
  // base total = 56,623,104 B (known safe); optional ref16 = +12,582,912 B
  const bool big = ws_size >= (size_t)69206016;
  unsigned short* ref16 = big ? (unsigned short*)ws : nullptr;
  const int use16 = big ? 1 : 0;

  proj_kernel<<<RQ / 32 + RK / 32, 256, 0, stream>>>(
      tgt, Wq, bq, ref, Wk, bk, Qb, Qlo, Kb, Klo);
  sim_cand_kernel<<<6 * 64 * 4, 256, 0, stream>>>(Qb, Kb, cand, ref, ref16, use16);
  out_kernel<<<RK / 4, 256, 0, stream>>>(Qb, Qlo, Kb, Klo, cand, ref, ref16, use16, out);
}

// Round 13
// 248.446 us; speedup vs baseline: 1.0708x; 1.0070x over previous
//
#include <hip/hip_runtime.h>
#include <hip/hip_fp16.h>
#include <stdint.h>

#define T_FRAMES 3
#define NTOK 4096
#define CH 256

typedef __attribute__((ext_vector_type(8))) short bf16x8;
typedef __attribute__((ext_vector_type(4))) float f32x4;
typedef __attribute__((address_space(1))) void gvoid;
typedef __attribute__((address_space(3))) void svoid;

__device__ __forceinline__ unsigned short f2bf_rne(float f) {
  union { float f; uint32_t u; } c; c.f = f;
  uint32_t u = c.u;
  return (unsigned short)((u + 0x7FFFu + ((u >> 16) & 1u)) >> 16);
}
__device__ __forceinline__ float bflo(uint32_t x) { return __uint_as_float(x << 16); }
__device__ __forceinline__ float bfhi(uint32_t x) { return __uint_as_float(x & 0xFFFF0000u); }

// ---------- merged projection: l2norm(X @ W + b) in fp64; store bf16 + f32 residual.
// r4 structure (measured optimum 115.5us x3) with ONE change: X staging is now
// WAVE-PRIVATE (wave w stages its own 8 rows into At[w][64][8]) -> ZERO barriers.
// Hot loop instructions otherwise identical: 4x ds_read_b128 wave-broadcast
// (At[wv][k][0..7] = 64B contiguous), same 32 FMA/k, bit-identical FMA order ->
// outputs byte-identical to r4. Staging ds_writes become ~8-way bank-conflicted
// (8 writes/chunk vs 256 reads + 512 FMA: noise).
// FAILED work-redistribution alternatives (do not re-attempt):
//   r7  double-buffer:  160-186us (2x LDS -> occupancy halved, TLP was binding)
//   r9  k-split 4-row:  126-131us (halved FMA per W-load)
//   r11 col-split 8x2:  133-141us (halved FMA per LDS-broadcast-read)
// DECISION RULE: if this is ~115us too, the idle is load latency, not barrier
// convoy -> proj is at its structural floor; declare roofline.
__global__ __launch_bounds__(256) void proj_kernel(
    const float* __restrict__ Xq, const float* __restrict__ Wq, const float* __restrict__ bq,
    const float* __restrict__ Xk, const float* __restrict__ Wk, const float* __restrict__ bk,
    unsigned short* __restrict__ Qb, float* __restrict__ Qlo,
    unsigned short* __restrict__ Kb, float* __restrict__ Klo)
{
  __shared__ double At[4][64][8];   // [wave][k][row-in-wave]; wave-private slices
  const int tid = threadIdx.x;
  int blk = blockIdx.x;
  const float *X, *W, *bias; unsigned short* Pb; float* Plo;
  if (blk < 256) { X = Xq; W = Wq; bias = bq; Pb = Qb; Plo = Qlo; }
  else           { X = Xk; W = Wk; bias = bk; Pb = Kb; Plo = Klo; blk -= 256; }
  const int rbase = blk * 32;
  const int wv = tid >> 6, lane = tid & 63;
  const int r0 = wv * 8;
  const int c4 = lane * 4;

  double acc[8][4];
  #pragma unroll
  for (int i = 0; i < 8; i++) {
    #pragma unroll
    for (int j = 0; j < 4; j++) acc[i][j] = (double)bias[c4 + j];
  }

  // wave-private staging: lane l owns row (l&7) of this wave, k-slice (l>>3)*8..+7
  const int srow_l = lane & 7;
  const int skq = (lane >> 3) * 8;
  const float* xrow = X + (size_t)(rbase + r0 + srow_l) * CH + skq;

  for (int kc = 0; kc < CH; kc += 64) {
    {
      const float4 v0 = *(const float4*)(xrow + kc);
      const float4 v1 = *(const float4*)(xrow + kc + 4);
      At[wv][skq + 0][srow_l] = (double)v0.x; At[wv][skq + 1][srow_l] = (double)v0.y;
      At[wv][skq + 2][srow_l] = (double)v0.z; At[wv][skq + 3][srow_l] = (double)v0.w;
      At[wv][skq + 4][srow_l] = (double)v1.x; At[wv][skq + 5][srow_l] = (double)v1.y;
      At[wv][skq + 6][srow_l] = (double)v1.z; At[wv][skq + 7][srow_l] = (double)v1.w;
    }
    // no barrier: writer wave == reader wave; compiler inserts lgkmcnt waits
    #pragma unroll 8
    for (int k = 0; k < 64; k++) {
      const float4 w4 = *(const float4*)(W + (size_t)(kc + k) * CH + c4);
      const double b0 = (double)w4.x, b1 = (double)w4.y;
      const double b2 = (double)w4.z, b3 = (double)w4.w;
      double a[8];
      #pragma unroll
      for (int i = 0; i < 4; i++) {
        const double2 ap = *(const double2*)&At[wv][k][2 * i];
        a[2*i] = ap.x; a[2*i+1] = ap.y;
      }
      #pragma unroll
      for (int i = 0; i < 8; i++) {
        acc[i][0] += a[i] * b0; acc[i][1] += a[i] * b1;
        acc[i][2] += a[i] * b2; acc[i][3] += a[i] * b3;
      }
    }
    // no barrier
  }

  #pragma unroll
  for (int i = 0; i < 8; i++) {
    double ss = acc[i][0]*acc[i][0] + acc[i][1]*acc[i][1]
              + acc[i][2]*acc[i][2] + acc[i][3]*acc[i][3];
    #pragma unroll
    for (int off = 32; off >= 1; off >>= 1) ss += __shfl_xor(ss, off);
    const double inv = 1.0 / sqrt(ss + 1e-12);
    const size_t base = (size_t)(rbase + r0 + i) * CH + c4;
    double vd[4]; float fb[4]; unsigned short us[4];
    #pragma unroll
    for (int j = 0; j < 4; j++) {
      vd[j] = acc[i][j] * inv;
      us[j] = f2bf_rne((float)vd[j]);
      fb[j] = __uint_as_float(((uint32_t)us[j]) << 16);
    }
    uint2 pk; pk.x = (uint32_t)us[0] | ((uint32_t)us[1] << 16);
    pk.y = (uint32_t)us[2] | ((uint32_t)us[3] << 16);
    *(uint2*)(Pb + base) = pk;
    float4 lo;
    lo.x = (float)(vd[0] - (double)fb[0]); lo.y = (float)(vd[1] - (double)fb[1]);
    lo.z = (float)(vd[2] - (double)fb[2]); lo.w = (float)(vd[3] - (double)fb[3]);
    *(float4*)(Plo + base) = lo;
  }
}

// ---------- sim (bf16 16x16x32 MFMA) + per-lane top-16 + 4-lane merge.
// Also emits the fp16 ref copy (4096 elems/block x 1536 blocks = exact cover):
// sim is VALU/MFMA-bound with idle VMEM, so the extra 38 MB streams for free.
// grid: bt(6) x qb(64) x rs(4); block 256 thr = 4 waves; wave = 16 q x 1024 r
// key = [22 value bits of (sim+2.0)][10-bit rloc]
__global__ __launch_bounds__(256, 4) void sim_cand_kernel(
    const unsigned short* __restrict__ Qb,
    const unsigned short* __restrict__ Kb,
    uint32_t* __restrict__ cand,
    const float* __restrict__ ref,
    unsigned short* __restrict__ ref16, int use16)
{
  __shared__ unsigned short kst[2][32 * 256];  // 2 x 16 KB, 16B-cols rotated by row
  const int bid = blockIdx.x;
  const int rs = bid & 3;
  const int qb = (bid >> 2) & 63;
  const int bt = bid >> 8;
  const int b = bt / T_FRAMES;
  const int tid = threadIdx.x;
  const int wv = tid >> 6, lane = tid & 63;
  const int lq = lane & 15, g = lane >> 4;
  const int q = qb * 64 + wv * 16 + lq;

  // fp16 ref copy: this block's 4096-element slice, coalesced 32B/lane reads
  if (use16) {
    #pragma unroll
    for (int pass = 0; pass < 2; pass++) {
      const size_t i = (size_t)bid * 4096 + (size_t)pass * 2048 + (size_t)tid * 8;
      const float4 v0 = *(const float4*)(ref + i);
      const float4 v1 = *(const float4*)(ref + i + 4);
      const uint32_t h0 = (uint32_t)__half_as_ushort(__float2half_rn(v0.x));
      const uint32_t h1 = (uint32_t)__half_as_ushort(__float2half_rn(v0.y));
      const uint32_t h2 = (uint32_t)__half_as_ushort(__float2half_rn(v0.z));
      const uint32_t h3 = (uint32_t)__half_as_ushort(__float2half_rn(v0.w));
      const uint32_t h4 = (uint32_t)__half_as_ushort(__float2half_rn(v1.x));
      const uint32_t h5 = (uint32_t)__half_as_ushort(__float2half_rn(v1.y));
      const uint32_t h6 = (uint32_t)__half_as_ushort(__float2half_rn(v1.z));
      const uint32_t h7 = (uint32_t)__half_as_ushort(__float2half_rn(v1.w));
      uint4 hv;
      hv.x = h0 | (h1 << 16); hv.y = h2 | (h3 << 16);
      hv.z = h4 | (h5 << 16); hv.w = h6 | (h7 << 16);
      *(uint4*)(ref16 + i) = hv;
    }
  }

  bf16x8 bfr[8];
  {
    const unsigned short* qrow = Qb + (size_t)(b * NTOK + q) * CH + g * 8;
    #pragma unroll
    for (int kc = 0; kc < 8; kc++) bfr[kc] = *(const bf16x8*)(qrow + kc * 32);
  }
  uint32_t best[16];
  #pragma unroll
  for (int i = 0; i < 16; i++) best[i] = 0u;
  uint32_t s[16];

  const unsigned short* kbase = Kb + ((size_t)bt * NTOK + (size_t)rs * 1024) * CH;

#define STAGE(C, BUFI)                                                          \
  {                                                                             \
    _Pragma("unroll")                                                           \
    for (int t = 0; t < 4; t++) {                                               \
      const int o16 = (wv * 4 + t) * 64 + lane;                                 \
      const int row = o16 >> 5, colp = o16 & 31;                                \
      const int col16 = (colp - row) & 31;                                      \
      const unsigned short* gsrc = kbase + (size_t)((C) * 32 + row) * CH + col16 * 8; \
      __builtin_amdgcn_global_load_lds((const gvoid*)gsrc,                      \
          (svoid*)(&kst[BUFI][0] + (size_t)(wv * 4 + t) * 512), 16, 0, 0);      \
    }                                                                           \
  }

#define COMPUTE_HALF(CBASE, BUFI, SOFF)                                         \
  {                                                                             \
    _Pragma("unroll")                                                           \
    for (int t = 0; t < 2; t++) {                                               \
      f32x4 acc = {2.0f, 2.0f, 2.0f, 2.0f};                                     \
      const int arow = t * 16 + lq;                                             \
      const unsigned short* rowp = &kst[BUFI][0] + (size_t)arow * 256;          \
      _Pragma("unroll")                                                         \
      for (int kc = 0; kc < 8; kc++) {                                          \
        const int colp = (kc * 4 + g + arow) & 31;                              \
        const bf16x8 a = *(const bf16x8*)(rowp + colp * 8);                     \
        acc = __builtin_amdgcn_mfma_f32_16x16x32_bf16(a, bfr[kc], acc, 0, 0, 0);\
      }                                                                         \
      _Pragma("unroll")                                                         \
      for (int j = 0; j < 4; j++) {                                             \
        const uint32_t bits = __float_as_uint(acc[j]);                          \
        s[(SOFF) + t * 4 + j] = (bits & 0xFFFFFC00u) |                          \
            (uint32_t)((CBASE) * 32 + t * 16 + g * 4 + j);                      \
      }                                                                         \
    }                                                                           \
  }

#define SORT16_MERGE()                                                          \
  {                                                                             \
    _Pragma("unroll")                                                           \
    for (int bk = 2; bk <= 16; bk <<= 1) {                                      \
      _Pragma("unroll")                                                         \
      for (int bj = bk >> 1; bj > 0; bj >>= 1) {                                \
        _Pragma("unroll")                                                       \
        for (int i = 0; i < 16; i++) {                                          \
          const int l = i ^ bj;                                                 \
          if (l > i) {                                                          \
            const bool up = ((i & bk) != 0);                                    \
            const uint32_t a2 = s[i], b2 = s[l];                                \
            const uint32_t mn = a2 < b2 ? a2 : b2;                              \
            const uint32_t mx = a2 < b2 ? b2 : a2;                              \
            s[i] = up ? mn : mx; s[l] = up ? mx : mn;                           \
          }                                                                     \
        }                                                                       \
      }                                                                         \
    }                                                                           \
    uint32_t m[16];                                                             \
    _Pragma("unroll")                                                           \
    for (int i = 0; i < 16; i++) {                                              \
      const uint32_t a2 = best[i], b2 = s[15 - i];                              \
      m[i] = a2 > b2 ? a2 : b2;                                                 \
    }                                                                           \
    _Pragma("unroll")                                                           \
    for (int bj = 8; bj > 0; bj >>= 1) {                                        \
      _Pragma("unroll")                                                         \
      for (int i = 0; i < 16; i++) {                                            \
        const int l = i ^ bj;                                                   \
        if (l > i) {                                                            \
          const uint32_t a2 = m[i], b2 = m[l];                                  \
          const uint32_t mn = a2 < b2 ? a2 : b2;                                \
          const uint32_t mx = a2 < b2 ? b2 : a2;                                \
          m[i] = mx; m[l] = mn;                                                 \
        }                                                                       \
      }                                                                         \
    }                                                                           \
    _Pragma("unroll")                                                           \
    for (int i = 0; i < 16; i++) best[i] = m[i];                                \
  }

  STAGE(0, 0);
  __syncthreads();
  for (int cp = 0; cp < 16; cp++) {
    const int c0 = 2 * cp;
    STAGE(c0 + 1, 1);
    COMPUTE_HALF(c0, 0, 0);
    __syncthreads();
    if (cp < 15) STAGE(c0 + 2, 0);
    COMPUTE_HALF(c0 + 1, 1, 8);
    SORT16_MERGE();
    __syncthreads();
  }

  #pragma unroll
  for (int st = 16; st <= 32; st <<= 1) {
    uint32_t o[16];
    #pragma unroll
    for (int i = 0; i < 16; i++) o[i] = (uint32_t)__shfl_xor((int)best[15 - i], st);
    #pragma unroll
    for (int i = 0; i < 16; i++) best[i] = best[i] > o[i] ? best[i] : o[i];
    #pragma unroll
    for (int bj = 8; bj > 0; bj >>= 1) {
      #pragma unroll
      for (int i = 0; i < 16; i++) {
        const int l = i ^ bj;
        if (l > i) {
          const uint32_t a2 = best[i], b2 = best[l];
          const uint32_t mn = a2 < b2 ? a2 : b2;
          const uint32_t mx = a2 < b2 ? b2 : a2;
          best[i] = mx; best[l] = mn;
        }
      }
    }
  }
  if (g == 0) {
    uint32_t* cp2 = cand + ((size_t)bt * NTOK + q) * 64 + rs * 16;
    #pragma unroll
    for (int i = 0; i < 16; i += 4) {
      uint4 v; v.x = best[i]; v.y = best[i+1]; v.z = best[i+2]; v.w = best[i+3];
      *(uint4*)(cp2 + i) = v;
    }
  }
#undef STAGE
#undef COMPUTE_HALF
#undef SORT16_MERGE
}

// ---------- final: sort 64 cands, fp64 band rescore (exact SET), softmax on
// mixed exact/coarse values, gather (fp16 copy when available).
// XCD-chunked swizzle keeps each XCD's gather working set L2-warm.
// BW = 2.5e-3: coarse-key error bound = quant 2.4e-4 + bf16 dot noise ~6e-4
// => E<=8.4e-4; band must exceed 2E=1.7e-3; 2.5e-3 keeps 1.5x margin.
__global__ __launch_bounds__(256) void out_kernel(
    const unsigned short* __restrict__ Qb, const float* __restrict__ Qlo,
    const unsigned short* __restrict__ Kb, const float* __restrict__ Klo,
    const uint32_t* __restrict__ cand, const float* __restrict__ ref,
    const unsigned short* __restrict__ ref16, int use16,
    float* __restrict__ out)
{
  const int tid = threadIdx.x, wv = tid >> 6, lane = tid & 63;
  const int bid = blockIdx.x;
  const int work = (bid & 7) * 768 + (bid >> 3);   // bijective, 6144 blocks
  const int rowid = work * 4 + wv;
  const int bt = rowid >> 12, q = rowid & 4095;
  const int b = bt / T_FRAMES;

  const uint32_t k0 = cand[(size_t)rowid * 64 + lane];
  uint32_t key = (k0 & 0xFFFFF000u) | ((uint32_t)(lane >> 4) << 10) | (k0 & 0x3FFu);

  // ascending bitonic-64, keys only (global r embedded in low 12 bits)
  #pragma unroll
  for (int k = 2; k <= 64; k <<= 1) {
    #pragma unroll
    for (int j = k >> 1; j > 0; j >>= 1) {
      const uint32_t ok = (uint32_t)__shfl_xor((int)key, j);
      const bool takeMax = (((lane & j) != 0) == ((lane & k) == 0));
      if ((ok > key) == takeMax) key = ok;
    }
  }
  const float v = __uint_as_float(key & 0xFFFFF000u) - 2.0f;
  int rr = (int)(key & 0xFFFu);

  const float v16c = __shfl(v, 48);
  const float BW = 2.5e-3f;
  const bool band = fabsf(v - v16c) <= BW;

  // reconstruct q channels lane*4..+3 in fp64
  const uint2 qbv = *(const uint2*)(Qb + (size_t)(b * NTOK + q) * CH + lane * 4);
  const float4 qlv = *(const float4*)(Qlo + (size_t)(b * NTOK + q) * CH + lane * 4);
  const double qd0 = (double)bflo(qbv.x) + (double)qlv.x;
  const double qd1 = (double)bfhi(qbv.x) + (double)qlv.y;
  const double qd2 = (double)bflo(qbv.y) + (double)qlv.z;
  const double qd3 = (double)bfhi(qbv.y) + (double)qlv.w;

  const unsigned short* kbp = Kb + (size_t)bt * NTOK * CH;
  const float* klp = Klo + (size_t)bt * NTOK * CH;

  double dval = -1.0e300;
  {
    const unsigned long long bm = __ballot(band);
    const int lo = __ffsll(bm) - 1;
    const int hi = 63 - __clzll(bm);
    for (int idx = lo; idx <= hi; idx++) {
      const int ri = __shfl(rr, idx);
      const uint2 kbv = *(const uint2*)(kbp + (size_t)ri * CH + lane * 4);
      const float4 klv = *(const float4*)(klp + (size_t)ri * CH + lane * 4);
      double dd = qd0 * ((double)bflo(kbv.x) + (double)klv.x)
                + qd1 * ((double)bfhi(kbv.x) + (double)klv.y)
                + qd2 * ((double)bflo(kbv.y) + (double)klv.z)
                + qd3 * ((double)bfhi(kbv.y) + (double)klv.w);
      #pragma unroll
      for (int off = 32; off >= 1; off >>= 1) dd += __shfl_xor(dd, off);
      if (lane == idx) dval = dd;
    }
  }
  double p = band ? dval : ((v > v16c + BW) ? (double)v : -1.0e300);

  // ascending bitonic on (p, rr): top-16 land in lanes 48..63.
  #pragma unroll
  for (int k = 2; k <= 64; k <<= 1) {
    #pragma unroll
    for (int j = k >> 1; j > 0; j >>= 1) {
      const double op = __shfl_xor(p, j);
      const int orr = __shfl_xor(rr, j);
      const bool takeMax = (((lane & j) != 0) == ((lane & k) == 0));
      const bool og = (op > p) || (op == p && orr < rr);
      if (takeMax == og) { p = op; rr = orr; }
    }
  }

  // softmax over lanes 48..63
  double pm = p;
  #pragma unroll
  for (int j = 8; j >= 1; j >>= 1) pm = fmax(pm, __shfl_xor(pm, j));
  double e = (lane >= 48) ? exp(p - pm) : 0.0;
  double es = e;
  #pragma unroll
  for (int j = 8; j >= 1; j >>= 1) es += __shfl_xor(es, j);
  const float w = (float)(e / es);

  float a0 = 0.f, a1 = 0.f, a2 = 0.f, a3 = 0.f;
  if (use16) {
    const unsigned short* rb16 = ref16 + (size_t)bt * NTOK * CH + lane * 4;
    #pragma unroll
    for (int i = 0; i < 16; i++) {
      const float wi = __shfl(w, 48 + i);
      const int ri = __shfl(rr, 48 + i) & 0xFFF;
      const uint2 hv = *(const uint2*)(rb16 + (size_t)ri * CH);
      a0 += wi * __half2float(__ushort_as_half((unsigned short)(hv.x & 0xFFFFu)));
      a1 += wi * __half2float(__ushort_as_half((unsigned short)(hv.x >> 16)));
      a2 += wi * __half2float(__ushort_as_half((unsigned short)(hv.y & 0xFFFFu)));
      a3 += wi * __half2float(__ushort_as_half((unsigned short)(hv.y >> 16)));
    }
  } else {
    const float* rbp = ref + (size_t)bt * NTOK * CH + lane * 4;
    #pragma unroll
    for (int i = 0; i < 16; i++) {
      const float wi = __shfl(w, 48 + i);
      const int ri = __shfl(rr, 48 + i) & 0xFFF;
      const float4 f = *(const float4*)(rbp + (size_t)ri * CH);
      a0 += wi * f.x; a1 += wi * f.y; a2 += wi * f.z; a3 += wi * f.w;
    }
  }
  float4 o; o.x = a0; o.y = a1; o.z = a2; o.w = a3;
  *(float4*)(out + (size_t)rowid * CH + lane * 4) = o;
}

extern "C" void kernel_launch(void* const* d_in, const int* in_sizes, int n_in,
                              void* d_out, int out_size, void* d_ws, size_t ws_size,
                              hipStream_t stream) {
  const float* tgt = (const float*)d_in[0];
  const float* ref = (const float*)d_in[1];
  const float* Wq  = (const float*)d_in[2];
  const float* bq  = (const float*)d_in[3];
  const float* Wk  = (const float*)d_in[4];
  const float* bk  = (const float*)d_in[5];
  float* out = (float*)d_out;

  const int B = 2;
  const int RQ = B * NTOK;            // 8192
  const int RK = B * T_FRAMES * NTOK; // 24576

  char* ws = (char*)d_ws;
  unsigned short* Qb = (unsigned short*)ws; ws += (size_t)RQ * CH * 2;  // 4.19 MB
  float* Qlo = (float*)ws;                  ws += (size_t)RQ * CH * 4;  // 8.39 MB
  unsigned short* Kb = (unsigned short*)ws; ws += (size_t)RK * CH * 2;  // 12.58 MB
  float* Klo = (float*)ws;                  ws += (size_t)RK * CH * 4;  // 25.17 MB
  uint32_t* cand = (uint32_t*)ws;           ws += (size_t)RK * 64 * 4;  // 6.29 MB
  // base total = 56,623,104 B (known safe); optional ref16 = +12,582,912 B
  const bool big = ws_size >= (size_t)69206016;
  unsigned short* ref16 = big ? (unsigned short*)ws : nullptr;
  const int use16 = big ? 1 : 0;

  proj_kernel<<<RQ / 32 + RK / 32, 256, 0, stream>>>(
      tgt, Wq, bq, ref, Wk, bk, Qb, Qlo, Kb, Klo);
  sim_cand_kernel<<<6 * 64 * 4, 256, 0, stream>>>(Qb, Kb, cand, ref, ref16, use16);
  out_kernel<<<RK / 4, 256, 0, stream>>>(Qb, Qlo, Kb, Klo, cand, ref, ref16, use16, out);
}